// Round 5
// baseline (1076.477 us; speedup 1.0000x reference)
//
#include <hip/hip_runtime.h>
#include <hip/hip_bf16.h>

typedef unsigned short u16;
typedef unsigned int u32;
typedef __bf16 bf16_8 __attribute__((ext_vector_type(8)));
typedef float f32x4 __attribute__((ext_vector_type(4)));

#define DEV __device__ __forceinline__

static const int T_TOK = 8192;    // B*S
static const int DM    = 1024;
static const int SEQ   = 2048;

DEV u16 f2b(float f) {
  union { float f; u32 u; } v; v.f = f;
  u32 r = v.u + 0x7fffu + ((v.u >> 16) & 1u);
  return (u16)(r >> 16);
}
DEV float b2f(u16 b) {
  union { u32 u; float f; } v; v.u = ((u32)b) << 16;
  return v.f;
}
DEV void gload16(void* lds, const void* g) {
  __builtin_amdgcn_global_load_lds((const __attribute__((address_space(1))) u32*)g,
                                   (__attribute__((address_space(3))) u32*)lds, 16, 0, 0);
}
DEV void vmdrain() { asm volatile("s_waitcnt vmcnt(0)" ::: "memory"); }

// ---------------- weight convert f32 -> bf16 ----------------
__global__ void cvt_bf16(const float* __restrict__ in, u16* __restrict__ out, int n) {
  int i = (blockIdx.x * blockDim.x + threadIdx.x) * 4;
  if (i >= n) return;
  float4 v = *(const float4*)(in + i);
  union { u16 h[4]; uint2 u; } pk;
  pk.h[0] = f2b(v.x); pk.h[1] = f2b(v.y); pk.h[2] = f2b(v.z); pk.h[3] = f2b(v.w);
  *(uint2*)(out + i) = pk.u;
}

// ---------------- RMSNorm: f32 row -> bf16 row ----------------
__launch_bounds__(256)
__global__ void rmsnorm_k(const float* __restrict__ x, const float* __restrict__ g,
                          u16* __restrict__ out) {
  const int row = blockIdx.x;
  const float4 v = ((const float4*)(x + (size_t)row * DM))[threadIdx.x];
  float ss = v.x*v.x + v.y*v.y + v.z*v.z + v.w*v.w;
  #pragma unroll
  for (int off = 1; off < 64; off <<= 1) ss += __shfl_xor(ss, off, 64);
  __shared__ float ws[4];
  if ((threadIdx.x & 63) == 0) ws[threadIdx.x >> 6] = ss;
  __syncthreads();
  float tot = ws[0] + ws[1] + ws[2] + ws[3];
  float inv = rsqrtf(tot * (1.0f / DM) + 1e-5f);
  const float4 gv = ((const float4*)g)[threadIdx.x];
  union { u16 h[4]; uint2 u; } pk;
  pk.h[0] = f2b(v.x * inv * gv.x);
  pk.h[1] = f2b(v.y * inv * gv.y);
  pk.h[2] = f2b(v.z * inv * gv.z);
  pk.h[3] = f2b(v.w * inv * gv.w);
  *(uint2*)(out + (size_t)row * DM + threadIdx.x * 4) = pk.u;
}

// ---------------- RoPE in-place on bf16 [T][1024] ----------------
__global__ void rope_k(u16* __restrict__ buf, float scale) {
  int idx = blockIdx.x * blockDim.x + threadIdx.x;    // pair index
  if (idx >= T_TOK * 512) return;
  int t = idx >> 9;
  int p = idx & 511;           // h*32 + d
  int d = p & 31;
  int s = t & (SEQ - 1);
  float inv = __expf(-(float)d * (logf(10000.0f) / 32.0f));
  float ang = (float)s * inv;
  float sn = sinf(ang), cs = cosf(ang);
  size_t off = (size_t)t * DM + (size_t)(p >> 5) * 64 + 2 * d;
  float x1 = b2f(buf[off]), x2 = b2f(buf[off + 1]);
  buf[off]     = f2b((x1 * cs - x2 * sn) * scale);
  buf[off + 1] = f2b((x1 * sn + x2 * cs) * scale);
}

// ---------------- generic NT GEMM: C[M][N] = A[M][K] * B[N][K]^T ----------------
// MODE 0: Cb = bf16(acc)
// MODE 1: Cf = resid + acc            (f32 out; resid = x, f32)
// MODE 2: Cb = bf16(silu(aux) * acc)  (SwiGLU; aux aliases Cb, in-place)
// MODE 3: Cf = resid + acc            (final output, f32; resid = Y, f32)
template<int MODE>
__launch_bounds__(256)
__global__ void gemm_nt(const u16* __restrict__ A, const u16* __restrict__ B,
                        u16* Cb, float* __restrict__ Cf,
                        const float* __restrict__ resid, const u16* aux,
                        int N, int K) {
  __shared__ __attribute__((aligned(16))) u16 As[128 * 32];
  __shared__ __attribute__((aligned(16))) u16 Bs[128 * 32];
  const int tid = threadIdx.x;
  const int w = tid >> 6, l = tid & 63;
  const int wr = w >> 1, wc = w & 1;
  const int brow = blockIdx.y * 128;
  const int bcol = blockIdx.x * 128;
  const int lr = l & 15, lg = l >> 4, lk = lg * 8;
  f32x4 acc[4][4] = {};

  for (int kk = 0; kk < K; kk += 32) {
    {
      int c = tid;   // chunk c: row c>>2, col (c&3)*8 of the [128][32] tile
      gload16((char*)As + (size_t)w * 1024,
              A + (size_t)(brow + (c >> 2)) * K + kk + (c & 3) * 8);
      gload16((char*)Bs + (size_t)w * 1024,
              B + (size_t)(bcol + (c >> 2)) * K + kk + (c & 3) * 8);
      c = tid + 256;
      gload16((char*)As + 4096 + (size_t)w * 1024,
              A + (size_t)(brow + (c >> 2)) * K + kk + (c & 3) * 8);
      gload16((char*)Bs + 4096 + (size_t)w * 1024,
              B + (size_t)(bcol + (c >> 2)) * K + kk + (c & 3) * 8);
    }
    vmdrain();
    __syncthreads();
    bf16_8 af[4], bf[4];
    #pragma unroll
    for (int m = 0; m < 4; ++m)
      af[m] = *(const bf16_8*)&As[(wr * 64 + m * 16 + lr) * 32 + lk];
    #pragma unroll
    for (int n = 0; n < 4; ++n)
      bf[n] = *(const bf16_8*)&Bs[(wc * 64 + n * 16 + lr) * 32 + lk];
    #pragma unroll
    for (int m = 0; m < 4; ++m)
      #pragma unroll
      for (int n = 0; n < 4; ++n)
        acc[m][n] = __builtin_amdgcn_mfma_f32_16x16x32_bf16(af[m], bf[n], acc[m][n], 0, 0, 0);
    __syncthreads();
  }

  #pragma unroll
  for (int m = 0; m < 4; ++m) {
    #pragma unroll
    for (int n = 0; n < 4; ++n) {
      #pragma unroll
      for (int r = 0; r < 4; ++r) {
        int row = brow + wr * 64 + m * 16 + lg * 4 + r;
        int col = bcol + wc * 64 + n * 16 + lr;
        size_t idx = (size_t)row * N + col;
        float v = acc[m][n][r];
        if (MODE == 0) {
          Cb[idx] = f2b(v);
        } else if (MODE == 1 || MODE == 3) {
          Cf[idx] = resid[idx] + v;
        } else if (MODE == 2) {
          float av = b2f(aux[idx]);
          float sig = 1.0f / (1.0f + __expf(-av));
          Cb[idx] = f2b(av * sig * v);
        }
      }
    }
  }
}

// ---------------- flash attention, causal (MFMA) ----------------
// grid: (S/64, B*H); 256 threads = 4 waves, wave w owns q rows [q0+16w, q0+16w+16)
__launch_bounds__(256)
__global__ void attn_k(const u16* __restrict__ Q, const u16* __restrict__ Kb,
                       const u16* __restrict__ V, u16* __restrict__ CTX) {
  __shared__ __attribute__((aligned(16))) u16 Ks[32 * 64];
  __shared__ __attribute__((aligned(16))) u16 Vt[64 * 32];
  __shared__ __attribute__((aligned(16))) u16 Ps[4][16 * 32];
  const int tid = threadIdx.x, w = tid >> 6, l = tid & 63;
  const int bh = blockIdx.y;
  const int b = bh >> 4, h = bh & 15;
  const int q0 = blockIdx.x * 64;
  const int lr = l & 15, lg = l >> 4, lk = lg * 8;
  const size_t base = (size_t)b * SEQ * DM + (size_t)h * 64;

  const size_t qrow = base + (size_t)(q0 + w * 16 + lr) * DM;
  const bf16_8 qf0 = *(const bf16_8*)&Q[qrow + lk];
  const bf16_8 qf1 = *(const bf16_8*)&Q[qrow + 32 + lk];

  f32x4 o[4] = {};
  float mrow[4], lsum[4];
  #pragma unroll
  for (int r = 0; r < 4; ++r) { mrow[r] = -3.0e38f; lsum[r] = 0.0f; }

  const int kv_end = q0 + 64;
  for (int kv0 = 0; kv0 < kv_end; kv0 += 32) {
    __syncthreads();      // protect LDS reuse
    gload16((char*)Ks + (size_t)w * 1024,
            Kb + base + (size_t)(kv0 + (tid >> 3)) * DM + (tid & 7) * 8);
    {
      const int vr = tid >> 3, vc = (tid & 7) * 8;
      uint4 raw = *(const uint4*)&V[base + (size_t)(kv0 + vr) * DM + vc];
      u16 e[8] = { (u16)raw.x, (u16)(raw.x >> 16), (u16)raw.y, (u16)(raw.y >> 16),
                   (u16)raw.z, (u16)(raw.z >> 16), (u16)raw.w, (u16)(raw.w >> 16) };
      #pragma unroll
      for (int j = 0; j < 8; ++j) Vt[(vc + j) * 32 + vr] = e[j];
    }
    vmdrain();
    __syncthreads();

    // S = Q K^T, two 16-col halves
    f32x4 s[2];
    #pragma unroll
    for (int h0 = 0; h0 < 2; ++h0) {
      bf16_8 k0 = *(const bf16_8*)&Ks[(h0 * 16 + lr) * 64 + lk];
      bf16_8 k1 = *(const bf16_8*)&Ks[(h0 * 16 + lr) * 64 + 32 + lk];
      f32x4 z = {};
      z = __builtin_amdgcn_mfma_f32_16x16x32_bf16(qf0, k0, z, 0, 0, 0);
      z = __builtin_amdgcn_mfma_f32_16x16x32_bf16(qf1, k1, z, 0, 0, 0);
      s[h0] = z;
    }

    // causal mask + online softmax (per output row r)
    #pragma unroll
    for (int r = 0; r < 4; ++r) {
      const int qg = q0 + w * 16 + lg * 4 + r;
      #pragma unroll
      for (int h0 = 0; h0 < 2; ++h0) {
        int kg = kv0 + h0 * 16 + lr;
        if (kg > qg) s[h0][r] = -3.0e38f;
      }
      float vmax = fmaxf(s[0][r], s[1][r]);
      #pragma unroll
      for (int off = 1; off < 16; off <<= 1) vmax = fmaxf(vmax, __shfl_xor(vmax, off, 64));
      float mnew = fmaxf(mrow[r], vmax);
      float alpha = __expf(mrow[r] - mnew);
      mrow[r] = mnew;
      float p0 = __expf(s[0][r] - mnew);
      float p1 = __expf(s[1][r] - mnew);
      s[0][r] = p0; s[1][r] = p1;
      float rs = p0 + p1;
      #pragma unroll
      for (int off = 1; off < 16; off <<= 1) rs += __shfl_xor(rs, off, 64);
      lsum[r] = lsum[r] * alpha + rs;
      o[0][r] *= alpha; o[1][r] *= alpha; o[2][r] *= alpha; o[3][r] *= alpha;
    }

    // P -> LDS (per-wave region), re-read as A fragment
    #pragma unroll
    for (int h0 = 0; h0 < 2; ++h0)
      #pragma unroll
      for (int r = 0; r < 4; ++r)
        Ps[w][(lg * 4 + r) * 32 + h0 * 16 + lr] = f2b(s[h0][r]);

    bf16_8 pf = *(const bf16_8*)&Ps[w][lr * 32 + lk];
    #pragma unroll
    for (int n = 0; n < 4; ++n) {
      bf16_8 vf = *(const bf16_8*)&Vt[(n * 16 + lr) * 32 + lk];
      o[n] = __builtin_amdgcn_mfma_f32_16x16x32_bf16(pf, vf, o[n], 0, 0, 0);
    }
  }

  #pragma unroll
  for (int n = 0; n < 4; ++n)
    #pragma unroll
    for (int r = 0; r < 4; ++r) {
      float v = o[n][r] / lsum[r];
      size_t row = (size_t)b * SEQ + q0 + w * 16 + lg * 4 + r;
      CTX[row * DM + h * 64 + n * 16 + lr] = f2b(v);
    }
}

// ---------------- launch ----------------
// ALL inputs f32 (reference dtypes); output f32. bf16 used internally only.
// workspace layout (MB): peak 144
//   [0,32)   bf16 weights: WQ 0, WK 2, WV 4, WO 6, W1 8, W3 16, W2 24
//   [32,48)  XN  (xn, later yn)
//   [48,64)  Qb   \
//   [64,80)  Kb    |-- dead after attn/WO; FFIN [48,112) reuses them
//   [80,96)  Vb    |
//   [96,112) CTX  /
//   [112,144) Y (f32)
extern "C" void kernel_launch(void* const* d_in, const int* in_sizes, int n_in,
                              void* d_out, int out_size, void* d_ws, size_t ws_size,
                              hipStream_t stream) {
  const float* x  = (const float*)d_in[0];
  const float* wq = (const float*)d_in[1];
  const float* wk = (const float*)d_in[2];
  const float* wv = (const float*)d_in[3];
  const float* wo = (const float*)d_in[4];
  const float* g1 = (const float*)d_in[5];
  const float* g2 = (const float*)d_in[6];
  const float* w1 = (const float*)d_in[7];
  const float* w2 = (const float*)d_in[8];   // [1024][4096]
  const float* w3 = (const float*)d_in[9];   // [4096][1024]

  char* ws = (char*)d_ws;
  const size_t MB = 1024 * 1024;
  u16*  WQb  = (u16*)(ws +  0 * MB);
  u16*  WKb  = (u16*)(ws +  2 * MB);
  u16*  WVb  = (u16*)(ws +  4 * MB);
  u16*  WOb  = (u16*)(ws +  6 * MB);
  u16*  W1b  = (u16*)(ws +  8 * MB);
  u16*  W3b  = (u16*)(ws + 16 * MB);
  u16*  W2b  = (u16*)(ws + 24 * MB);
  u16*  XN   = (u16*)(ws + 32 * MB);   // xn, later yn
  u16*  Qb   = (u16*)(ws + 48 * MB);
  u16*  Kb   = (u16*)(ws + 64 * MB);
  u16*  Vb   = (u16*)(ws + 80 * MB);
  u16*  CTX  = (u16*)(ws + 96 * MB);
  float* Y   = (float*)(ws + 112 * MB);
  u16*  FFIN = (u16*)(ws + 48 * MB);   // reuses Qb..CTX (dead after WO gemm)

  // weights -> bf16
  cvt_bf16<<<1024, 256, 0, stream>>>(wq, WQb, 1048576);
  cvt_bf16<<<1024, 256, 0, stream>>>(wk, WKb, 1048576);
  cvt_bf16<<<1024, 256, 0, stream>>>(wv, WVb, 1048576);
  cvt_bf16<<<1024, 256, 0, stream>>>(wo, WOb, 1048576);
  cvt_bf16<<<4096, 256, 0, stream>>>(w1, W1b, 4194304);
  cvt_bf16<<<4096, 256, 0, stream>>>(w3, W3b, 4194304);
  cvt_bf16<<<4096, 256, 0, stream>>>(w2, W2b, 4194304);

  // xn = rmsnorm(x, g1)
  rmsnorm_k<<<T_TOK, 256, 0, stream>>>(x, g1, XN);

  // Q,K,V projections
  gemm_nt<0><<<dim3(8, 64), 256, 0, stream>>>(XN, WQb, Qb, nullptr, nullptr, nullptr, 1024, 1024);
  gemm_nt<0><<<dim3(8, 64), 256, 0, stream>>>(XN, WKb, Kb, nullptr, nullptr, nullptr, 1024, 1024);
  gemm_nt<0><<<dim3(8, 64), 256, 0, stream>>>(XN, WVb, Vb, nullptr, nullptr, nullptr, 1024, 1024);

  // RoPE (scale 1/sqrt(dk) folded into Q)
  rope_k<<<16384, 256, 0, stream>>>(Qb, 0.125f);
  rope_k<<<16384, 256, 0, stream>>>(Kb, 1.0f);

  // attention
  attn_k<<<dim3(32, 64), 256, 0, stream>>>(Qb, Kb, Vb, CTX);

  // y = x + ctx @ wo^T   (f32)
  gemm_nt<1><<<dim3(8, 64), 256, 0, stream>>>(CTX, WOb, nullptr, Y, x, nullptr, 1024, 1024);

  // yn = rmsnorm(y, g2)
  rmsnorm_k<<<T_TOK, 256, 0, stream>>>(Y, g2, XN);

  // a = yn @ w1^T ; ffin = silu(a) * (yn @ w3^T)   (in-place on FFIN)
  gemm_nt<0><<<dim3(32, 64), 256, 0, stream>>>(XN, W1b, FFIN, nullptr, nullptr, nullptr, 4096, 1024);
  gemm_nt<2><<<dim3(32, 64), 256, 0, stream>>>(XN, W3b, FFIN, nullptr, nullptr, FFIN, 4096, 1024);

  // out = y + ffin @ w2^T  (f32 output!)
  gemm_nt<3><<<dim3(8, 64), 256, 0, stream>>>(FFIN, W2b, nullptr, (float*)d_out, Y, nullptr, 1024, 4096);
}

// Round 6
// 774.238 us; speedup vs baseline: 1.3904x; 1.3904x over previous
//
#include <hip/hip_runtime.h>
#include <hip/hip_bf16.h>

typedef unsigned short u16;
typedef unsigned int u32;
typedef __bf16 bf16_8 __attribute__((ext_vector_type(8)));
typedef float f32x4 __attribute__((ext_vector_type(4)));

#define DEV __device__ __forceinline__

static const int T_TOK = 8192;    // B*S
static const int DM    = 1024;
static const int SEQ   = 2048;

DEV u16 f2b(float f) {
  union { float f; u32 u; } v; v.f = f;
  u32 r = v.u + 0x7fffu + ((v.u >> 16) & 1u);
  return (u16)(r >> 16);
}
DEV float b2f(u16 b) {
  union { u32 u; float f; } v; v.u = ((u32)b) << 16;
  return v.f;
}
DEV void gload16(void* lds, const void* g) {
  __builtin_amdgcn_global_load_lds((const __attribute__((address_space(1))) u32*)g,
                                   (__attribute__((address_space(3))) u32*)lds, 16, 0, 0);
}
DEV void vmdrain() { asm volatile("s_waitcnt vmcnt(0)" ::: "memory"); }
DEV uint2 tr_read(u32 addr) {
  uint2 r;
  asm volatile("ds_read_b64_tr_b16 %0, %1" : "=v"(r) : "v"(addr));
  return r;
}

// ---------------- weight convert f32 -> bf16 ----------------
__global__ void cvt_bf16(const float* __restrict__ in, u16* __restrict__ out, int n) {
  int i = (blockIdx.x * blockDim.x + threadIdx.x) * 4;
  if (i >= n) return;
  float4 v = *(const float4*)(in + i);
  union { u16 h[4]; uint2 u; } pk;
  pk.h[0] = f2b(v.x); pk.h[1] = f2b(v.y); pk.h[2] = f2b(v.z); pk.h[3] = f2b(v.w);
  *(uint2*)(out + i) = pk.u;
}

// ---------------- RMSNorm: f32 row -> bf16 row ----------------
__launch_bounds__(256)
__global__ void rmsnorm_k(const float* __restrict__ x, const float* __restrict__ g,
                          u16* __restrict__ out) {
  const int row = blockIdx.x;
  const float4 v = ((const float4*)(x + (size_t)row * DM))[threadIdx.x];
  float ss = v.x*v.x + v.y*v.y + v.z*v.z + v.w*v.w;
  #pragma unroll
  for (int off = 1; off < 64; off <<= 1) ss += __shfl_xor(ss, off, 64);
  __shared__ float ws[4];
  if ((threadIdx.x & 63) == 0) ws[threadIdx.x >> 6] = ss;
  __syncthreads();
  float tot = ws[0] + ws[1] + ws[2] + ws[3];
  float inv = rsqrtf(tot * (1.0f / DM) + 1e-5f);
  const float4 gv = ((const float4*)g)[threadIdx.x];
  union { u16 h[4]; uint2 u; } pk;
  pk.h[0] = f2b(v.x * inv * gv.x);
  pk.h[1] = f2b(v.y * inv * gv.y);
  pk.h[2] = f2b(v.z * inv * gv.z);
  pk.h[3] = f2b(v.w * inv * gv.w);
  *(uint2*)(out + (size_t)row * DM + threadIdx.x * 4) = pk.u;
}

// ---------------- RoPE in-place on bf16 [T][1024] ----------------
__global__ void rope_k(u16* __restrict__ buf, float scale) {
  int idx = blockIdx.x * blockDim.x + threadIdx.x;    // pair index
  if (idx >= T_TOK * 512) return;
  int t = idx >> 9;
  int p = idx & 511;           // h*32 + d
  int d = p & 31;
  int s = t & (SEQ - 1);
  float inv = __expf(-(float)d * (logf(10000.0f) / 32.0f));
  float ang = (float)s * inv;
  float sn = sinf(ang), cs = cosf(ang);
  size_t off = (size_t)t * DM + (size_t)(p >> 5) * 64 + 2 * d;
  float x1 = b2f(buf[off]), x2 = b2f(buf[off + 1]);
  buf[off]     = f2b((x1 * cs - x2 * sn) * scale);
  buf[off + 1] = f2b((x1 * sn + x2 * cs) * scale);
}

// ---------------- generic NT GEMM: C[M][N] = A[M][K] * B[N][K]^T ----------------
// MODE 0: Cb = bf16(acc)
// MODE 1: Cf = resid + acc            (f32 out; resid = x, f32)
// MODE 2: Cb = bf16(silu(aux) * acc)  (SwiGLU; aux aliases Cb, in-place)
// MODE 3: Cf = resid + acc            (final output, f32; resid = Y, f32)
template<int MODE>
__launch_bounds__(256)
__global__ void gemm_nt(const u16* __restrict__ A, const u16* __restrict__ B,
                        u16* Cb, float* __restrict__ Cf,
                        const float* __restrict__ resid, const u16* aux,
                        int N, int K) {
  __shared__ __attribute__((aligned(16))) u16 As[128 * 32];
  __shared__ __attribute__((aligned(16))) u16 Bs[128 * 32];
  const int tid = threadIdx.x;
  const int w = tid >> 6, l = tid & 63;
  const int wr = w >> 1, wc = w & 1;
  // XCD-aware bijective block swizzle (nwg % 8 == 0 for all our launches)
  const int nwg = gridDim.x * gridDim.y;
  const int id  = blockIdx.y * gridDim.x + blockIdx.x;
  const int nid = (id & 7) * (nwg >> 3) + (id >> 3);
  const int bx = nid % gridDim.x, by = nid / gridDim.x;
  const int brow = by * 128;
  const int bcol = bx * 128;
  const int lr = l & 15, lg = l >> 4, lk = lg * 8;
  f32x4 acc[4][4] = {};

  for (int kk = 0; kk < K; kk += 32) {
    {
      int c = tid;   // chunk c: row c>>2, col (c&3)*8 of the [128][32] tile
      gload16((char*)As + (size_t)w * 1024,
              A + (size_t)(brow + (c >> 2)) * K + kk + (c & 3) * 8);
      gload16((char*)Bs + (size_t)w * 1024,
              B + (size_t)(bcol + (c >> 2)) * K + kk + (c & 3) * 8);
      c = tid + 256;
      gload16((char*)As + 4096 + (size_t)w * 1024,
              A + (size_t)(brow + (c >> 2)) * K + kk + (c & 3) * 8);
      gload16((char*)Bs + 4096 + (size_t)w * 1024,
              B + (size_t)(bcol + (c >> 2)) * K + kk + (c & 3) * 8);
    }
    vmdrain();
    __syncthreads();
    bf16_8 af[4], bf[4];
    #pragma unroll
    for (int m = 0; m < 4; ++m)
      af[m] = *(const bf16_8*)&As[(wr * 64 + m * 16 + lr) * 32 + lk];
    #pragma unroll
    for (int n = 0; n < 4; ++n)
      bf[n] = *(const bf16_8*)&Bs[(wc * 64 + n * 16 + lr) * 32 + lk];
    #pragma unroll
    for (int m = 0; m < 4; ++m)
      #pragma unroll
      for (int n = 0; n < 4; ++n)
        acc[m][n] = __builtin_amdgcn_mfma_f32_16x16x32_bf16(af[m], bf[n], acc[m][n], 0, 0, 0);
    __syncthreads();
  }

  #pragma unroll
  for (int m = 0; m < 4; ++m) {
    #pragma unroll
    for (int n = 0; n < 4; ++n) {
      #pragma unroll
      for (int r = 0; r < 4; ++r) {
        int row = brow + wr * 64 + m * 16 + lg * 4 + r;
        int col = bcol + wc * 64 + n * 16 + lr;
        size_t idx = (size_t)row * N + col;
        float v = acc[m][n][r];
        if (MODE == 0) {
          Cb[idx] = f2b(v);
        } else if (MODE == 1 || MODE == 3) {
          Cf[idx] = resid[idx] + v;
        } else if (MODE == 2) {
          float av = b2f(aux[idx]);
          float sig = 1.0f / (1.0f + __expf(-av));
          Cb[idx] = f2b(av * sig * v);
        }
      }
    }
  }
}

// ---------------- flash attention v2, causal (MFMA) ----------------
// grid: (16, B*H); 256 threads = 4 waves; block handles q-tiles {bx, 31-bx}
// (uniform 33 KV-steps per block). KVBLK=64.
// K LDS: [64][64] bf16, XOR-swizzled (elem ^= (row&7)<<3), staged by
//   global_load_lds with pre-swizzled SOURCE (LDS dest linear — rule 21).
// V LDS: subtiled [kv/4][d/16][4][16], consumed via ds_read_b64_tr_b16 (T10).
// Ps: per-wave [16][64], XOR-swizzled both sides.
__launch_bounds__(256)
__global__ void attn_k(const u16* __restrict__ Q, const u16* __restrict__ Kb,
                       const u16* __restrict__ V, u16* __restrict__ CTX) {
  __shared__ __attribute__((aligned(16))) u16 Ks[64 * 64];
  __shared__ __attribute__((aligned(16))) u16 Vs[64 * 64];
  __shared__ __attribute__((aligned(16))) u16 Ps[4][16 * 64];
  const int tid = threadIdx.x, w = tid >> 6, l = tid & 63;
  const int bh = blockIdx.y;
  const int b = bh >> 4, h = bh & 15;
  const int lr = l & 15, lg = l >> 4;
  const size_t base = (size_t)b * SEQ * DM + (size_t)h * 64;
  const u32 vs_base = (u32)(size_t)&Vs[0];

  #pragma unroll 1
  for (int pass = 0; pass < 2; ++pass) {
    const int qt = pass ? (31 - blockIdx.x) : blockIdx.x;
    const int q0 = qt * 64;

    const size_t qrow = base + (size_t)(q0 + w * 16 + lr) * DM;
    bf16_8 qf0 = *(const bf16_8*)&Q[qrow + lg * 8];
    bf16_8 qf1 = *(const bf16_8*)&Q[qrow + 32 + lg * 8];

    f32x4 o[4] = {};
    float mrow[4], lsum[4];
    #pragma unroll
    for (int r = 0; r < 4; ++r) { mrow[r] = -3.0e38f; lsum[r] = 0.0f; }

    for (int kv0 = 0; kv0 < q0 + 64; kv0 += 64) {
      __syncthreads();     // protect K/V LDS reuse
      {
        // K tile: linear LDS dest, swizzled source col
        int u = tid, row = u >> 3, slot = u & 7;
        gload16((char*)Ks + (size_t)w * 1024,
                Kb + base + (size_t)(kv0 + row) * DM + ((slot * 8) ^ ((row & 7) << 3)));
        u = tid + 256; row = u >> 3; slot = u & 7;
        gload16((char*)Ks + 4096 + (size_t)w * 1024,
                Kb + base + (size_t)(kv0 + row) * DM + ((slot * 8) ^ ((row & 7) << 3)));
        // V tile: subtiled layout via source mapping (LDS dest linear)
        u = tid;
        int kv = ((u >> 5) << 2) + ((u >> 1) & 3);
        int d  = (((u >> 3) & 3) << 4) + ((u & 1) << 3);
        gload16((char*)Vs + (size_t)w * 1024,
                V + base + (size_t)(kv0 + kv) * DM + d);
        u = tid + 256;
        kv = ((u >> 5) << 2) + ((u >> 1) & 3);
        d  = (((u >> 3) & 3) << 4) + ((u & 1) << 3);
        gload16((char*)Vs + 4096 + (size_t)w * 1024,
                V + base + (size_t)(kv0 + kv) * DM + d);
      }
      vmdrain();
      __syncthreads();

      // S = Q K^T  (4 col-groups of 16, K over 64)
      f32x4 s[4];
      #pragma unroll
      for (int h0 = 0; h0 < 4; ++h0) {
        const int row = h0 * 16 + lr;
        bf16_8 k0 = *(const bf16_8*)&Ks[row * 64 + ((lg * 8) ^ ((lr & 7) << 3))];
        bf16_8 k1 = *(const bf16_8*)&Ks[row * 64 + ((32 + lg * 8) ^ ((lr & 7) << 3))];
        f32x4 z = {};
        z = __builtin_amdgcn_mfma_f32_16x16x32_bf16(qf0, k0, z, 0, 0, 0);
        z = __builtin_amdgcn_mfma_f32_16x16x32_bf16(qf1, k1, z, 0, 0, 0);
        s[h0] = z;
      }

      // causal mask + online softmax + P write (per output row r)
      #pragma unroll
      for (int r = 0; r < 4; ++r) {
        const int qg = q0 + w * 16 + lg * 4 + r;
        #pragma unroll
        for (int h0 = 0; h0 < 4; ++h0) {
          int kg = kv0 + h0 * 16 + lr;
          if (kg > qg) s[h0][r] = -3.0e38f;
        }
        float vmax = fmaxf(fmaxf(s[0][r], s[1][r]), fmaxf(s[2][r], s[3][r]));
        #pragma unroll
        for (int off = 1; off < 16; off <<= 1) vmax = fmaxf(vmax, __shfl_xor(vmax, off, 64));
        float mnew = fmaxf(mrow[r], vmax);
        float alpha = __expf(mrow[r] - mnew);
        mrow[r] = mnew;
        float p[4], rs = 0.0f;
        #pragma unroll
        for (int h0 = 0; h0 < 4; ++h0) { p[h0] = __expf(s[h0][r] - mnew); rs += p[h0]; }
        #pragma unroll
        for (int off = 1; off < 16; off <<= 1) rs += __shfl_xor(rs, off, 64);
        lsum[r] = lsum[r] * alpha + rs;
        o[0][r] *= alpha; o[1][r] *= alpha; o[2][r] *= alpha; o[3][r] *= alpha;
        const int ql = lg * 4 + r;
        #pragma unroll
        for (int h0 = 0; h0 < 4; ++h0)
          Ps[w][ql * 64 + (((h0 * 16 + lr) ^ ((ql & 7) << 3)))] = f2b(p[h0]);
      }

      // PV: o += P(16x64) * V(64x64); V^T fragments via ds_read_b64_tr_b16
      #pragma unroll
      for (int kc = 0; kc < 2; ++kc) {
        bf16_8 pf = *(const bf16_8*)&Ps[w][lr * 64 + (((kc * 32 + lg * 8) ^ ((lr & 7) << 3)))];
        uint2 t0[4], t1[4];
        #pragma unroll
        for (int n = 0; n < 4; ++n) {
          u32 a0 = vs_base + (u32)((((kc * 8 + lg * 2 + 0) * 4 + n) * 128) + lr * 8);
          u32 a1 = vs_base + (u32)((((kc * 8 + lg * 2 + 1) * 4 + n) * 128) + lr * 8);
          t0[n] = tr_read(a0);
          t1[n] = tr_read(a1);
        }
        asm volatile("s_waitcnt lgkmcnt(0)" ::: "memory");
        __builtin_amdgcn_sched_barrier(0);
        #pragma unroll
        for (int n = 0; n < 4; ++n) {
          union { uint2 u2[2]; bf16_8 v; } vf;
          vf.u2[0] = t0[n]; vf.u2[1] = t1[n];
          o[n] = __builtin_amdgcn_mfma_f32_16x16x32_bf16(pf, vf.v, o[n], 0, 0, 0);
        }
      }
    }

    #pragma unroll
    for (int r = 0; r < 4; ++r) {
      float inv = 1.0f / lsum[r];
      size_t row = (size_t)b * SEQ + q0 + w * 16 + lg * 4 + r;
      #pragma unroll
      for (int n = 0; n < 4; ++n)
        CTX[row * DM + h * 64 + n * 16 + lr] = f2b(o[n][r] * inv);
    }
  }
}

// ---------------- launch ----------------
// ALL inputs f32 (reference dtypes); output f32. bf16 used internally only.
// workspace layout (MB): peak 144
//   [0,32)   bf16 weights: WQ 0, WK 2, WV 4, WO 6, W1 8, W3 16, W2 24
//   [32,48)  XN  (xn, later yn)
//   [48,64)  Qb   \
//   [64,80)  Kb    |-- dead after attn/WO; FFIN [48,112) reuses them
//   [80,96)  Vb    |
//   [96,112) CTX  /
//   [112,144) Y (f32)
extern "C" void kernel_launch(void* const* d_in, const int* in_sizes, int n_in,
                              void* d_out, int out_size, void* d_ws, size_t ws_size,
                              hipStream_t stream) {
  const float* x  = (const float*)d_in[0];
  const float* wq = (const float*)d_in[1];
  const float* wk = (const float*)d_in[2];
  const float* wv = (const float*)d_in[3];
  const float* wo = (const float*)d_in[4];
  const float* g1 = (const float*)d_in[5];
  const float* g2 = (const float*)d_in[6];
  const float* w1 = (const float*)d_in[7];
  const float* w2 = (const float*)d_in[8];   // [1024][4096]
  const float* w3 = (const float*)d_in[9];   // [4096][1024]

  char* ws = (char*)d_ws;
  const size_t MB = 1024 * 1024;
  u16*  WQb  = (u16*)(ws +  0 * MB);
  u16*  WKb  = (u16*)(ws +  2 * MB);
  u16*  WVb  = (u16*)(ws +  4 * MB);
  u16*  WOb  = (u16*)(ws +  6 * MB);
  u16*  W1b  = (u16*)(ws +  8 * MB);
  u16*  W3b  = (u16*)(ws + 16 * MB);
  u16*  W2b  = (u16*)(ws + 24 * MB);
  u16*  XN   = (u16*)(ws + 32 * MB);   // xn, later yn
  u16*  Qb   = (u16*)(ws + 48 * MB);
  u16*  Kb   = (u16*)(ws + 64 * MB);
  u16*  Vb   = (u16*)(ws + 80 * MB);
  u16*  CTX  = (u16*)(ws + 96 * MB);
  float* Y   = (float*)(ws + 112 * MB);
  u16*  FFIN = (u16*)(ws + 48 * MB);   // reuses Qb..CTX (dead after WO gemm)

  // weights -> bf16
  cvt_bf16<<<1024, 256, 0, stream>>>(wq, WQb, 1048576);
  cvt_bf16<<<1024, 256, 0, stream>>>(wk, WKb, 1048576);
  cvt_bf16<<<1024, 256, 0, stream>>>(wv, WVb, 1048576);
  cvt_bf16<<<1024, 256, 0, stream>>>(wo, WOb, 1048576);
  cvt_bf16<<<4096, 256, 0, stream>>>(w1, W1b, 4194304);
  cvt_bf16<<<4096, 256, 0, stream>>>(w3, W3b, 4194304);
  cvt_bf16<<<4096, 256, 0, stream>>>(w2, W2b, 4194304);

  // xn = rmsnorm(x, g1)
  rmsnorm_k<<<T_TOK, 256, 0, stream>>>(x, g1, XN);

  // Q,K,V projections
  gemm_nt<0><<<dim3(8, 64), 256, 0, stream>>>(XN, WQb, Qb, nullptr, nullptr, nullptr, 1024, 1024);
  gemm_nt<0><<<dim3(8, 64), 256, 0, stream>>>(XN, WKb, Kb, nullptr, nullptr, nullptr, 1024, 1024);
  gemm_nt<0><<<dim3(8, 64), 256, 0, stream>>>(XN, WVb, Vb, nullptr, nullptr, nullptr, 1024, 1024);

  // RoPE (scale 1/sqrt(dk) folded into Q)
  rope_k<<<16384, 256, 0, stream>>>(Qb, 0.125f);
  rope_k<<<16384, 256, 0, stream>>>(Kb, 1.0f);

  // attention
  attn_k<<<dim3(16, 64), 256, 0, stream>>>(Qb, Kb, Vb, CTX);

  // y = x + ctx @ wo^T   (f32)
  gemm_nt<1><<<dim3(8, 64), 256, 0, stream>>>(CTX, WOb, nullptr, Y, x, nullptr, 1024, 1024);

  // yn = rmsnorm(y, g2)
  rmsnorm_k<<<T_TOK, 256, 0, stream>>>(Y, g2, XN);

  // a = yn @ w1^T ; ffin = silu(a) * (yn @ w3^T)   (in-place on FFIN)
  gemm_nt<0><<<dim3(32, 64), 256, 0, stream>>>(XN, W1b, FFIN, nullptr, nullptr, nullptr, 4096, 1024);
  gemm_nt<2><<<dim3(32, 64), 256, 0, stream>>>(XN, W3b, FFIN, nullptr, nullptr, FFIN, 4096, 1024);

  // out = y + ffin @ w2^T  (f32 output)
  gemm_nt<3><<<dim3(8, 64), 256, 0, stream>>>(FFIN, W2b, nullptr, (float*)d_out, Y, nullptr, 1024, 4096);
}

// Round 7
// 750.529 us; speedup vs baseline: 1.4343x; 1.0316x over previous
//
#include <hip/hip_runtime.h>
#include <hip/hip_bf16.h>

typedef unsigned short u16;
typedef unsigned int u32;
typedef __bf16 bf16_8 __attribute__((ext_vector_type(8)));
typedef float f32x4 __attribute__((ext_vector_type(4)));

#define DEV __device__ __forceinline__

static const int T_TOK = 8192;    // B*S
static const int DM    = 1024;
static const int SEQ   = 2048;

DEV u16 f2b(float f) {
  union { float f; u32 u; } v; v.f = f;
  u32 r = v.u + 0x7fffu + ((v.u >> 16) & 1u);
  return (u16)(r >> 16);
}
DEV float b2f(u16 b) {
  union { u32 u; float f; } v; v.u = ((u32)b) << 16;
  return v.f;
}
DEV void gload16(void* lds, const void* g) {
  __builtin_amdgcn_global_load_lds((const __attribute__((address_space(1))) u32*)g,
                                   (__attribute__((address_space(3))) u32*)lds, 16, 0, 0);
}
DEV void vmdrain() { asm volatile("s_waitcnt vmcnt(0)" ::: "memory"); }
DEV uint2 tr_read(u32 addr) {
  uint2 r;
  asm volatile("ds_read_b64_tr_b16 %0, %1" : "=v"(r) : "v"(addr));
  return r;
}

// ---------------- weight convert f32 -> bf16 ----------------
__global__ void cvt_bf16(const float* __restrict__ in, u16* __restrict__ out, int n) {
  int i = (blockIdx.x * blockDim.x + threadIdx.x) * 4;
  if (i >= n) return;
  float4 v = *(const float4*)(in + i);
  union { u16 h[4]; uint2 u; } pk;
  pk.h[0] = f2b(v.x); pk.h[1] = f2b(v.y); pk.h[2] = f2b(v.z); pk.h[3] = f2b(v.w);
  *(uint2*)(out + i) = pk.u;
}

// ---------------- RMSNorm: f32 row -> bf16 row ----------------
__launch_bounds__(256)
__global__ void rmsnorm_k(const float* __restrict__ x, const float* __restrict__ g,
                          u16* __restrict__ out) {
  const int row = blockIdx.x;
  const float4 v = ((const float4*)(x + (size_t)row * DM))[threadIdx.x];
  float ss = v.x*v.x + v.y*v.y + v.z*v.z + v.w*v.w;
  #pragma unroll
  for (int off = 1; off < 64; off <<= 1) ss += __shfl_xor(ss, off, 64);
  __shared__ float ws[4];
  if ((threadIdx.x & 63) == 0) ws[threadIdx.x >> 6] = ss;
  __syncthreads();
  float tot = ws[0] + ws[1] + ws[2] + ws[3];
  float inv = rsqrtf(tot * (1.0f / DM) + 1e-5f);
  const float4 gv = ((const float4*)g)[threadIdx.x];
  union { u16 h[4]; uint2 u; } pk;
  pk.h[0] = f2b(v.x * inv * gv.x);
  pk.h[1] = f2b(v.y * inv * gv.y);
  pk.h[2] = f2b(v.z * inv * gv.z);
  pk.h[3] = f2b(v.w * inv * gv.w);
  *(uint2*)(out + (size_t)row * DM + threadIdx.x * 4) = pk.u;
}

// ---------------- RoPE in-place on bf16 [T][1024] ----------------
__global__ void rope_k(u16* __restrict__ buf, float scale) {
  int idx = blockIdx.x * blockDim.x + threadIdx.x;    // pair index
  if (idx >= T_TOK * 512) return;
  int t = idx >> 9;
  int p = idx & 511;           // h*32 + d
  int d = p & 31;
  int s = t & (SEQ - 1);
  float inv = __expf(-(float)d * (logf(10000.0f) / 32.0f));
  float ang = (float)s * inv;
  float sn = sinf(ang), cs = cosf(ang);
  size_t off = (size_t)t * DM + (size_t)(p >> 5) * 64 + 2 * d;
  float x1 = b2f(buf[off]), x2 = b2f(buf[off + 1]);
  buf[off]     = f2b((x1 * cs - x2 * sn) * scale);
  buf[off + 1] = f2b((x1 * sn + x2 * cs) * scale);
}

// ======== shared GEMM core pieces (128x128 tile, BK=32, XOR-swizzled LDS) ===
// LDS logical: tile[row][chunk(8elem)] stored at slot (row*4 + (chunk ^ ((row>>1)&3))).
// Staging keeps LDS dest linear; SOURCE carries the same involution (rule 21).
// Read: chunk' = lg ^ ((lr>>1)&3)  -> lanes 0..7 hit 8 distinct 16B granules.

#define GEMM_STAGE(As, Bs, Ap, Bp, K)                                          \
  {                                                                            \
    int c = tid;                                                               \
    gload16((char*)As + (size_t)w * 1024,                                      \
            Ap + (size_t)(brow + (c >> 2)) * K + kk + (((c & 3) ^ ((c >> 3) & 3)) << 3)); \
    gload16((char*)Bs + (size_t)w * 1024,                                      \
            Bp + (size_t)(bcol + (c >> 2)) * K + kk + (((c & 3) ^ ((c >> 3) & 3)) << 3)); \
    c = tid + 256;                                                             \
    gload16((char*)As + 4096 + (size_t)w * 1024,                               \
            Ap + (size_t)(brow + (c >> 2)) * K + kk + (((c & 3) ^ ((c >> 3) & 3)) << 3)); \
    gload16((char*)Bs + 4096 + (size_t)w * 1024,                               \
            Bp + (size_t)(bcol + (c >> 2)) * K + kk + (((c & 3) ^ ((c >> 3) & 3)) << 3)); \
  }

#define GEMM_MFMA(As, Bs)                                                      \
  {                                                                            \
    const int swz = ((lr >> 1) & 3) ^ lg;                                      \
    bf16_8 af[4], bfr[4];                                                      \
    _Pragma("unroll")                                                          \
    for (int m = 0; m < 4; ++m)                                                \
      af[m] = *(const bf16_8*)&As[(wr * 64 + m * 16 + lr) * 32 + (swz << 3)];  \
    _Pragma("unroll")                                                          \
    for (int n = 0; n < 4; ++n)                                                \
      bfr[n] = *(const bf16_8*)&Bs[(wc * 64 + n * 16 + lr) * 32 + (swz << 3)]; \
    _Pragma("unroll")                                                          \
    for (int m = 0; m < 4; ++m)                                                \
      _Pragma("unroll")                                                        \
      for (int n = 0; n < 4; ++n)                                              \
        acc[m][n] = __builtin_amdgcn_mfma_f32_16x16x32_bf16(af[m], bfr[n], acc[m][n], 0, 0, 0); \
  }

// ---------------- generic NT GEMM: C[M][N] = A[M][K] * B[N][K]^T ----------------
// MODE 0: Cb = bf16(acc)
// MODE 1: Cf = resid + acc            (f32 out; resid = x, f32)
// MODE 2: Cb = bf16(silu(aux) * acc)  (SwiGLU; aux aliases Cb, in-place)
// MODE 3: Cf = resid + acc            (final output, f32; resid = Y, f32)
template<int MODE>
__launch_bounds__(256)
__global__ void gemm_nt(const u16* __restrict__ A, const u16* __restrict__ B,
                        u16* Cb, float* __restrict__ Cf,
                        const float* __restrict__ resid, const u16* aux,
                        int N, int K) {
  __shared__ __attribute__((aligned(16))) u16 As[128 * 32];
  __shared__ __attribute__((aligned(16))) u16 Bs[128 * 32];
  const int tid = threadIdx.x;
  const int w = tid >> 6, l = tid & 63;
  const int wr = w >> 1, wc = w & 1;
  // XCD-aware bijective block swizzle (nwg % 8 == 0 for all our launches)
  const int nwg = gridDim.x * gridDim.y;
  const int id  = blockIdx.y * gridDim.x + blockIdx.x;
  const int nid = (id & 7) * (nwg >> 3) + (id >> 3);
  const int bx = nid % gridDim.x, by = nid / gridDim.x;
  const int brow = by * 128;
  const int bcol = bx * 128;
  const int lr = l & 15, lg = l >> 4;
  f32x4 acc[4][4] = {};

  for (int kk = 0; kk < K; kk += 32) {
    GEMM_STAGE(As, Bs, A, B, K)
    vmdrain();
    __syncthreads();
    GEMM_MFMA(As, Bs)
    __syncthreads();
  }

  #pragma unroll
  for (int m = 0; m < 4; ++m) {
    #pragma unroll
    for (int n = 0; n < 4; ++n) {
      #pragma unroll
      for (int r = 0; r < 4; ++r) {
        int row = brow + wr * 64 + m * 16 + lg * 4 + r;
        int col = bcol + wc * 64 + n * 16 + lr;
        size_t idx = (size_t)row * N + col;
        float v = acc[m][n][r];
        if (MODE == 0) {
          Cb[idx] = f2b(v);
        } else if (MODE == 1 || MODE == 3) {
          Cf[idx] = resid[idx] + v;
        } else if (MODE == 2) {
          float av = b2f(aux[idx]);
          float sig = 1.0f / (1.0f + __expf(-av));
          Cb[idx] = f2b(av * sig * v);
        }
      }
    }
  }
}

// ---------------- fused QKV projection: 3 GEMMs in one launch ----------------
// grid (24, 64): col-blocks 0..7 -> Q, 8..15 -> K, 16..23 -> V. All selects
// wave-uniform (SGPR). N = K = 1024 for each output.
__launch_bounds__(256)
__global__ void gemm_qkv(const u16* __restrict__ A,
                         const u16* __restrict__ Bq, const u16* __restrict__ Bk,
                         const u16* __restrict__ Bv,
                         u16* __restrict__ Oq, u16* __restrict__ Ok,
                         u16* __restrict__ Ov) {
  __shared__ __attribute__((aligned(16))) u16 As[128 * 32];
  __shared__ __attribute__((aligned(16))) u16 Bs[128 * 32];
  const int tid = threadIdx.x;
  const int w = tid >> 6, l = tid & 63;
  const int wr = w >> 1, wc = w & 1;
  const int nwg = gridDim.x * gridDim.y;          // 1536, %8==0
  const int id  = blockIdx.y * gridDim.x + blockIdx.x;
  const int nid = (id & 7) * (nwg >> 3) + (id >> 3);
  const int bx = nid % gridDim.x, by = nid / gridDim.x;
  const int brow = by * 128;
  const int mi = bx >> 3;                          // 0=Q 1=K 2=V
  const int bcol = (bx & 7) * 128;
  const u16* B = (mi == 0) ? Bq : (mi == 1) ? Bk : Bv;
  u16* O = (mi == 0) ? Oq : (mi == 1) ? Ok : Ov;
  const int lr = l & 15, lg = l >> 4;
  const int K = 1024;
  f32x4 acc[4][4] = {};

  for (int kk = 0; kk < K; kk += 32) {
    GEMM_STAGE(As, Bs, A, B, K)
    vmdrain();
    __syncthreads();
    GEMM_MFMA(As, Bs)
    __syncthreads();
  }

  #pragma unroll
  for (int m = 0; m < 4; ++m)
    #pragma unroll
    for (int n = 0; n < 4; ++n)
      #pragma unroll
      for (int r = 0; r < 4; ++r) {
        int row = brow + wr * 64 + m * 16 + lg * 4 + r;
        int col = bcol + wc * 64 + n * 16 + lr;
        O[(size_t)row * 1024 + col] = f2b(acc[m][n][r]);
      }
}

// ---------------- flash attention v2, causal (MFMA) ----------------
// grid: (16, B*H); 256 threads = 4 waves; block handles q-tiles {bx, 31-bx}
// (uniform 33 KV-steps per block). KVBLK=64.
__launch_bounds__(256)
__global__ void attn_k(const u16* __restrict__ Q, const u16* __restrict__ Kb,
                       const u16* __restrict__ V, u16* __restrict__ CTX) {
  __shared__ __attribute__((aligned(16))) u16 Ks[64 * 64];
  __shared__ __attribute__((aligned(16))) u16 Vs[64 * 64];
  __shared__ __attribute__((aligned(16))) u16 Ps[4][16 * 64];
  const int tid = threadIdx.x, w = tid >> 6, l = tid & 63;
  const int bh = blockIdx.y;
  const int b = bh >> 4, h = bh & 15;
  const int lr = l & 15, lg = l >> 4;
  const size_t base = (size_t)b * SEQ * DM + (size_t)h * 64;
  const u32 vs_base = (u32)(size_t)&Vs[0];

  #pragma unroll 1
  for (int pass = 0; pass < 2; ++pass) {
    const int qt = pass ? (31 - blockIdx.x) : blockIdx.x;
    const int q0 = qt * 64;

    const size_t qrow = base + (size_t)(q0 + w * 16 + lr) * DM;
    bf16_8 qf0 = *(const bf16_8*)&Q[qrow + lg * 8];
    bf16_8 qf1 = *(const bf16_8*)&Q[qrow + 32 + lg * 8];

    f32x4 o[4] = {};
    float mrow[4], lsum[4];
    #pragma unroll
    for (int r = 0; r < 4; ++r) { mrow[r] = -3.0e38f; lsum[r] = 0.0f; }

    for (int kv0 = 0; kv0 < q0 + 64; kv0 += 64) {
      __syncthreads();     // protect K/V LDS reuse
      {
        int u = tid, row = u >> 3, slot = u & 7;
        gload16((char*)Ks + (size_t)w * 1024,
                Kb + base + (size_t)(kv0 + row) * DM + ((slot * 8) ^ ((row & 7) << 3)));
        u = tid + 256; row = u >> 3; slot = u & 7;
        gload16((char*)Ks + 4096 + (size_t)w * 1024,
                Kb + base + (size_t)(kv0 + row) * DM + ((slot * 8) ^ ((row & 7) << 3)));
        u = tid;
        int kv = ((u >> 5) << 2) + ((u >> 1) & 3);
        int d  = (((u >> 3) & 3) << 4) + ((u & 1) << 3);
        gload16((char*)Vs + (size_t)w * 1024,
                V + base + (size_t)(kv0 + kv) * DM + d);
        u = tid + 256;
        kv = ((u >> 5) << 2) + ((u >> 1) & 3);
        d  = (((u >> 3) & 3) << 4) + ((u & 1) << 3);
        gload16((char*)Vs + 4096 + (size_t)w * 1024,
                V + base + (size_t)(kv0 + kv) * DM + d);
      }
      vmdrain();
      __syncthreads();

      // S = Q K^T  (4 col-groups of 16, K over 64)
      f32x4 s[4];
      #pragma unroll
      for (int h0 = 0; h0 < 4; ++h0) {
        const int row = h0 * 16 + lr;
        bf16_8 k0 = *(const bf16_8*)&Ks[row * 64 + ((lg * 8) ^ ((lr & 7) << 3))];
        bf16_8 k1 = *(const bf16_8*)&Ks[row * 64 + ((32 + lg * 8) ^ ((lr & 7) << 3))];
        f32x4 z = {};
        z = __builtin_amdgcn_mfma_f32_16x16x32_bf16(qf0, k0, z, 0, 0, 0);
        z = __builtin_amdgcn_mfma_f32_16x16x32_bf16(qf1, k1, z, 0, 0, 0);
        s[h0] = z;
      }

      // causal mask + online softmax + P write (per output row r)
      #pragma unroll
      for (int r = 0; r < 4; ++r) {
        const int qg = q0 + w * 16 + lg * 4 + r;
        #pragma unroll
        for (int h0 = 0; h0 < 4; ++h0) {
          int kg = kv0 + h0 * 16 + lr;
          if (kg > qg) s[h0][r] = -3.0e38f;
        }
        float vmax = fmaxf(fmaxf(s[0][r], s[1][r]), fmaxf(s[2][r], s[3][r]));
        #pragma unroll
        for (int off = 1; off < 16; off <<= 1) vmax = fmaxf(vmax, __shfl_xor(vmax, off, 64));
        float mnew = fmaxf(mrow[r], vmax);
        float alpha = __expf(mrow[r] - mnew);
        mrow[r] = mnew;
        float p[4], rs = 0.0f;
        #pragma unroll
        for (int h0 = 0; h0 < 4; ++h0) { p[h0] = __expf(s[h0][r] - mnew); rs += p[h0]; }
        #pragma unroll
        for (int off = 1; off < 16; off <<= 1) rs += __shfl_xor(rs, off, 64);
        lsum[r] = lsum[r] * alpha + rs;
        o[0][r] *= alpha; o[1][r] *= alpha; o[2][r] *= alpha; o[3][r] *= alpha;
        const int ql = lg * 4 + r;
        #pragma unroll
        for (int h0 = 0; h0 < 4; ++h0)
          Ps[w][ql * 64 + (((h0 * 16 + lr) ^ ((ql & 7) << 3)))] = f2b(p[h0]);
      }

      // PV: o += P(16x64) * V(64x64); V^T fragments via ds_read_b64_tr_b16
      #pragma unroll
      for (int kc = 0; kc < 2; ++kc) {
        bf16_8 pf = *(const bf16_8*)&Ps[w][lr * 64 + (((kc * 32 + lg * 8) ^ ((lr & 7) << 3)))];
        uint2 t0[4], t1[4];
        #pragma unroll
        for (int n = 0; n < 4; ++n) {
          u32 a0 = vs_base + (u32)((((kc * 8 + lg * 2 + 0) * 4 + n) * 128) + lr * 8);
          u32 a1 = vs_base + (u32)((((kc * 8 + lg * 2 + 1) * 4 + n) * 128) + lr * 8);
          t0[n] = tr_read(a0);
          t1[n] = tr_read(a1);
        }
        asm volatile("s_waitcnt lgkmcnt(0)" ::: "memory");
        __builtin_amdgcn_sched_barrier(0);
        #pragma unroll
        for (int n = 0; n < 4; ++n) {
          union { uint2 u2[2]; bf16_8 v; } vf;
          vf.u2[0] = t0[n]; vf.u2[1] = t1[n];
          o[n] = __builtin_amdgcn_mfma_f32_16x16x32_bf16(pf, vf.v, o[n], 0, 0, 0);
        }
      }
    }

    #pragma unroll
    for (int r = 0; r < 4; ++r) {
      float inv = 1.0f / lsum[r];
      size_t row = (size_t)b * SEQ + q0 + w * 16 + lg * 4 + r;
      #pragma unroll
      for (int n = 0; n < 4; ++n)
        CTX[row * DM + h * 64 + n * 16 + lr] = f2b(o[n][r] * inv);
    }
  }
}

// ---------------- launch ----------------
// ALL inputs f32 (reference dtypes); output f32. bf16 used internally only.
// workspace layout (MB): peak 144
//   [0,32)   bf16 weights: WQ 0, WK 2, WV 4, WO 6, W1 8, W3 16, W2 24
//   [32,48)  XN  (xn, later yn)
//   [48,64)  Qb   \
//   [64,80)  Kb    |-- dead after attn/WO; FFIN [48,112) reuses them
//   [80,96)  Vb    |
//   [96,112) CTX  /
//   [112,144) Y (f32)
extern "C" void kernel_launch(void* const* d_in, const int* in_sizes, int n_in,
                              void* d_out, int out_size, void* d_ws, size_t ws_size,
                              hipStream_t stream) {
  const float* x  = (const float*)d_in[0];
  const float* wq = (const float*)d_in[1];
  const float* wk = (const float*)d_in[2];
  const float* wv = (const float*)d_in[3];
  const float* wo = (const float*)d_in[4];
  const float* g1 = (const float*)d_in[5];
  const float* g2 = (const float*)d_in[6];
  const float* w1 = (const float*)d_in[7];
  const float* w2 = (const float*)d_in[8];   // [1024][4096]
  const float* w3 = (const float*)d_in[9];   // [4096][1024]

  char* ws = (char*)d_ws;
  const size_t MB = 1024 * 1024;
  u16*  WQb  = (u16*)(ws +  0 * MB);
  u16*  WKb  = (u16*)(ws +  2 * MB);
  u16*  WVb  = (u16*)(ws +  4 * MB);
  u16*  WOb  = (u16*)(ws +  6 * MB);
  u16*  W1b  = (u16*)(ws +  8 * MB);
  u16*  W3b  = (u16*)(ws + 16 * MB);
  u16*  W2b  = (u16*)(ws + 24 * MB);
  u16*  XN   = (u16*)(ws + 32 * MB);   // xn, later yn
  u16*  Qb   = (u16*)(ws + 48 * MB);
  u16*  Kb   = (u16*)(ws + 64 * MB);
  u16*  Vb   = (u16*)(ws + 80 * MB);
  u16*  CTX  = (u16*)(ws + 96 * MB);
  float* Y   = (float*)(ws + 112 * MB);
  u16*  FFIN = (u16*)(ws + 48 * MB);   // reuses Qb..CTX (dead after WO gemm)

  // weights -> bf16
  cvt_bf16<<<1024, 256, 0, stream>>>(wq, WQb, 1048576);
  cvt_bf16<<<1024, 256, 0, stream>>>(wk, WKb, 1048576);
  cvt_bf16<<<1024, 256, 0, stream>>>(wv, WVb, 1048576);
  cvt_bf16<<<1024, 256, 0, stream>>>(wo, WOb, 1048576);
  cvt_bf16<<<4096, 256, 0, stream>>>(w1, W1b, 4194304);
  cvt_bf16<<<4096, 256, 0, stream>>>(w3, W3b, 4194304);
  cvt_bf16<<<4096, 256, 0, stream>>>(w2, W2b, 4194304);

  // xn = rmsnorm(x, g1)
  rmsnorm_k<<<T_TOK, 256, 0, stream>>>(x, g1, XN);

  // Q,K,V projections (fused)
  gemm_qkv<<<dim3(24, 64), 256, 0, stream>>>(XN, WQb, WKb, WVb, Qb, Kb, Vb);

  // RoPE (scale 1/sqrt(dk) folded into Q)
  rope_k<<<16384, 256, 0, stream>>>(Qb, 0.125f);
  rope_k<<<16384, 256, 0, stream>>>(Kb, 1.0f);

  // attention
  attn_k<<<dim3(16, 64), 256, 0, stream>>>(Qb, Kb, Vb, CTX);

  // y = x + ctx @ wo^T   (f32)
  gemm_nt<1><<<dim3(8, 64), 256, 0, stream>>>(CTX, WOb, nullptr, Y, x, nullptr, 1024, 1024);

  // yn = rmsnorm(y, g2)
  rmsnorm_k<<<T_TOK, 256, 0, stream>>>(Y, g2, XN);

  // a = yn @ w1^T ; ffin = silu(a) * (yn @ w3^T)   (in-place on FFIN)
  gemm_nt<0><<<dim3(32, 64), 256, 0, stream>>>(XN, W1b, FFIN, nullptr, nullptr, nullptr, 4096, 1024);
  gemm_nt<2><<<dim3(32, 64), 256, 0, stream>>>(XN, W3b, FFIN, nullptr, nullptr, FFIN, 4096, 1024);

  // out = y + ffin @ w2^T  (f32 output)
  gemm_nt<3><<<dim3(8, 64), 256, 0, stream>>>(FFIN, W2b, nullptr, (float*)d_out, Y, nullptr, 1024, 4096);
}

// Round 8
// 672.206 us; speedup vs baseline: 1.6014x; 1.1165x over previous
//
#include <hip/hip_runtime.h>
#include <hip/hip_bf16.h>

typedef unsigned short u16;
typedef unsigned int u32;
typedef __bf16 bf16_8 __attribute__((ext_vector_type(8)));
typedef float f32x4 __attribute__((ext_vector_type(4)));

#define DEV __device__ __forceinline__

static const int T_TOK = 8192;    // B*S
static const int DM    = 1024;
static const int SEQ   = 2048;

DEV u16 f2b(float f) {
  union { float f; u32 u; } v; v.f = f;
  u32 r = v.u + 0x7fffu + ((v.u >> 16) & 1u);
  return (u16)(r >> 16);
}
DEV float b2f(u16 b) {
  union { u32 u; float f; } v; v.u = ((u32)b) << 16;
  return v.f;
}
DEV void gload16(void* lds, const void* g) {
  __builtin_amdgcn_global_load_lds((const __attribute__((address_space(1))) u32*)g,
                                   (__attribute__((address_space(3))) u32*)lds, 16, 0, 0);
}
DEV uint2 tr_read(u32 addr) {
  uint2 r;
  asm volatile("ds_read_b64_tr_b16 %0, %1" : "=v"(r) : "v"(addr));
  return r;
}
#define VMCNT4 asm volatile("s_waitcnt vmcnt(4)" ::: "memory")
#define VMCNT0 asm volatile("s_waitcnt vmcnt(0)" ::: "memory")
#define SBAR   __builtin_amdgcn_s_barrier()
#define SCHED0 __builtin_amdgcn_sched_barrier(0)

// ---------------- weight convert f32 -> bf16 ----------------
__global__ void cvt_bf16(const float* __restrict__ in, u16* __restrict__ out, int n) {
  int i = (blockIdx.x * blockDim.x + threadIdx.x) * 4;
  if (i >= n) return;
  float4 v = *(const float4*)(in + i);
  union { u16 h[4]; uint2 u; } pk;
  pk.h[0] = f2b(v.x); pk.h[1] = f2b(v.y); pk.h[2] = f2b(v.z); pk.h[3] = f2b(v.w);
  *(uint2*)(out + i) = pk.u;
}

// ---------------- RMSNorm: f32 row -> bf16 row ----------------
__launch_bounds__(256)
__global__ void rmsnorm_k(const float* __restrict__ x, const float* __restrict__ g,
                          u16* __restrict__ out) {
  const int row = blockIdx.x;
  const float4 v = ((const float4*)(x + (size_t)row * DM))[threadIdx.x];
  float ss = v.x*v.x + v.y*v.y + v.z*v.z + v.w*v.w;
  #pragma unroll
  for (int off = 1; off < 64; off <<= 1) ss += __shfl_xor(ss, off, 64);
  __shared__ float ws[4];
  if ((threadIdx.x & 63) == 0) ws[threadIdx.x >> 6] = ss;
  __syncthreads();
  float tot = ws[0] + ws[1] + ws[2] + ws[3];
  float inv = rsqrtf(tot * (1.0f / DM) + 1e-5f);
  const float4 gv = ((const float4*)g)[threadIdx.x];
  union { u16 h[4]; uint2 u; } pk;
  pk.h[0] = f2b(v.x * inv * gv.x);
  pk.h[1] = f2b(v.y * inv * gv.y);
  pk.h[2] = f2b(v.z * inv * gv.z);
  pk.h[3] = f2b(v.w * inv * gv.w);
  *(uint2*)(out + (size_t)row * DM + threadIdx.x * 4) = pk.u;
}

// ---------------- RoPE in-place on bf16 [T][1024] ----------------
__global__ void rope_k(u16* __restrict__ buf, float scale) {
  int idx = blockIdx.x * blockDim.x + threadIdx.x;    // pair index
  if (idx >= T_TOK * 512) return;
  int t = idx >> 9;
  int p = idx & 511;           // h*32 + d
  int d = p & 31;
  int s = t & (SEQ - 1);
  float inv = __expf(-(float)d * (logf(10000.0f) / 32.0f));
  float ang = (float)s * inv;
  float sn = sinf(ang), cs = cosf(ang);
  size_t off = (size_t)t * DM + (size_t)(p >> 5) * 64 + 2 * d;
  float x1 = b2f(buf[off]), x2 = b2f(buf[off + 1]);
  buf[off]     = f2b((x1 * cs - x2 * sn) * scale);
  buf[off + 1] = f2b((x1 * sn + x2 * cs) * scale);
}

// ======== GEMM core (128x128 tile, BK=32, XOR-swizzled LDS, 2-phase dbuf) ===
// LDS logical: tile[row][chunk(8elem)] at slot (chunk ^ ((row>>1)&3)).
// Staging keeps LDS dest linear; SOURCE carries the involution (rule 21).

#define GEMM_STAGE(d, kk)                                                       \
  {                                                                             \
    int c = tid;                                                                \
    gload16((char*)As + (d) * 8192 + (size_t)w * 1024,                          \
            A + (size_t)(brow + (c >> 2)) * K + (kk) + (((c & 3) ^ ((c >> 3) & 3)) << 3)); \
    gload16((char*)Bs + (d) * 8192 + (size_t)w * 1024,                          \
            B + (size_t)(bcol + (c >> 2)) * K + (kk) + (((c & 3) ^ ((c >> 3) & 3)) << 3)); \
    c = tid + 256;                                                              \
    gload16((char*)As + (d) * 8192 + 4096 + (size_t)w * 1024,                   \
            A + (size_t)(brow + (c >> 2)) * K + (kk) + (((c & 3) ^ ((c >> 3) & 3)) << 3)); \
    gload16((char*)Bs + (d) * 8192 + 4096 + (size_t)w * 1024,                   \
            B + (size_t)(bcol + (c >> 2)) * K + (kk) + (((c & 3) ^ ((c >> 3) & 3)) << 3)); \
  }

#define GEMM_MFMA(d)                                                            \
  {                                                                             \
    const u16* Ab = &As[d][0]; const u16* Bb = &Bs[d][0];                       \
    const int swz = (((lr >> 1) & 3) ^ lg) << 3;                                \
    bf16_8 af[4], bfr[4];                                                       \
    _Pragma("unroll")                                                           \
    for (int m = 0; m < 4; ++m)                                                 \
      af[m] = *(const bf16_8*)&Ab[(wr * 64 + m * 16 + lr) * 32 + swz];          \
    _Pragma("unroll")                                                           \
    for (int n = 0; n < 4; ++n)                                                 \
      bfr[n] = *(const bf16_8*)&Bb[(wc * 64 + n * 16 + lr) * 32 + swz];         \
    _Pragma("unroll")                                                           \
    for (int m = 0; m < 4; ++m)                                                 \
      _Pragma("unroll")                                                         \
      for (int n = 0; n < 4; ++n)                                               \
        acc[m][n] = __builtin_amdgcn_mfma_f32_16x16x32_bf16(af[m], bfr[n], acc[m][n], 0, 0, 0); \
  }

#define GEMM_LOOP                                                               \
  const int nt = K >> 5;                                                        \
  GEMM_STAGE(0, 0)                                                              \
  int cur = 0;                                                                  \
  for (int t = 0; t < nt; ++t) {                                                \
    if (t + 1 < nt) { GEMM_STAGE(cur ^ 1, (t + 1) * 32) VMCNT4; }               \
    else VMCNT0;                                                                \
    SBAR; SCHED0;                                                               \
    GEMM_MFMA(cur)                                                              \
    SCHED0; SBAR;                                                               \
    cur ^= 1;                                                                   \
  }

// ---------------- generic NT GEMM: C[M][N] = A[M][K] * B[N][K]^T ----------------
// MODE 0: Cb = bf16(acc)
// MODE 1: Cf = resid + acc            (f32 out; resid = x, f32)
// MODE 2: Cb = bf16(silu(aux) * acc)  (SwiGLU; aux aliases Cb, in-place)
// MODE 3: Cf = resid + acc            (final output, f32; resid = Y, f32)
template<int MODE>
__launch_bounds__(256)
__global__ void gemm_nt(const u16* __restrict__ A, const u16* __restrict__ B,
                        u16* Cb, float* __restrict__ Cf,
                        const float* __restrict__ resid, const u16* aux,
                        int N, int K) {
  __shared__ __attribute__((aligned(16))) u16 As[2][128 * 32];
  __shared__ __attribute__((aligned(16))) u16 Bs[2][128 * 32];
  const int tid = threadIdx.x;
  const int w = tid >> 6, l = tid & 63;
  const int wr = w >> 1, wc = w & 1;
  const int nwg = gridDim.x * gridDim.y;
  const int id  = blockIdx.y * gridDim.x + blockIdx.x;
  const int nid = (id & 7) * (nwg >> 3) + (id >> 3);
  const int bx = nid % gridDim.x, by = nid / gridDim.x;
  const int brow = by * 128;
  const int bcol = bx * 128;
  const int lr = l & 15, lg = l >> 4;
  f32x4 acc[4][4] = {};

  GEMM_LOOP

  #pragma unroll
  for (int m = 0; m < 4; ++m) {
    #pragma unroll
    for (int n = 0; n < 4; ++n) {
      #pragma unroll
      for (int r = 0; r < 4; ++r) {
        int row = brow + wr * 64 + m * 16 + lg * 4 + r;
        int col = bcol + wc * 64 + n * 16 + lr;
        size_t idx = (size_t)row * N + col;
        float v = acc[m][n][r];
        if (MODE == 0) {
          Cb[idx] = f2b(v);
        } else if (MODE == 1 || MODE == 3) {
          Cf[idx] = resid[idx] + v;
        } else if (MODE == 2) {
          float av = b2f(aux[idx]);
          float sig = 1.0f / (1.0f + __expf(-av));
          Cb[idx] = f2b(av * sig * v);
        }
      }
    }
  }
}

// ---------------- fused QKV projection: 3 GEMMs in one launch ----------------
__launch_bounds__(256)
__global__ void gemm_qkv(const u16* __restrict__ A,
                         const u16* __restrict__ Bq, const u16* __restrict__ Bk,
                         const u16* __restrict__ Bv,
                         u16* __restrict__ Oq, u16* __restrict__ Ok,
                         u16* __restrict__ Ov) {
  __shared__ __attribute__((aligned(16))) u16 As[2][128 * 32];
  __shared__ __attribute__((aligned(16))) u16 Bs[2][128 * 32];
  const int tid = threadIdx.x;
  const int w = tid >> 6, l = tid & 63;
  const int wr = w >> 1, wc = w & 1;
  const int nwg = gridDim.x * gridDim.y;          // 1536, %8==0
  const int id  = blockIdx.y * gridDim.x + blockIdx.x;
  const int nid = (id & 7) * (nwg >> 3) + (id >> 3);
  const int bx = nid % gridDim.x, by = nid / gridDim.x;
  const int brow = by * 128;
  const int mi = bx >> 3;                          // 0=Q 1=K 2=V
  const int bcol = (bx & 7) * 128;
  const u16* B = (mi == 0) ? Bq : (mi == 1) ? Bk : Bv;
  u16* O = (mi == 0) ? Oq : (mi == 1) ? Ok : Ov;
  const int lr = l & 15, lg = l >> 4;
  const int K = 1024;
  f32x4 acc[4][4] = {};

  GEMM_LOOP

  #pragma unroll
  for (int m = 0; m < 4; ++m)
    #pragma unroll
    for (int n = 0; n < 4; ++n)
      #pragma unroll
      for (int r = 0; r < 4; ++r) {
        int row = brow + wr * 64 + m * 16 + lg * 4 + r;
        int col = bcol + wc * 64 + n * 16 + lr;
        O[(size_t)row * 1024 + col] = f2b(acc[m][n][r]);
      }
}

// ---------------- flash attention v3: swapped QK^T, dbuf K/V, causal ----------------
// grid (16, 64); 4 waves; block -> (bh, qx) via XCD remap so each XCD's
// resident blocks share 8 heads' KV (4MB = L2). Block does q-tiles {qx, 31-qx}.
// Swapped QK^T: s[h0][reg] = S[kv = kv0+h0*16+lg*4+reg][q = q0+w*16+lr]
// -> softmax row stats are lane-local for q=lr (15 ops + 2 shfl).
__launch_bounds__(256)
__global__ void attn_k(const u16* __restrict__ Q, const u16* __restrict__ Kb,
                       const u16* __restrict__ V, u16* __restrict__ CTX) {
  __shared__ __attribute__((aligned(16))) u16 Ks[2][64 * 64];
  __shared__ __attribute__((aligned(16))) u16 Vs[2][64 * 64];
  __shared__ __attribute__((aligned(16))) u16 Ps[4][16 * 64];
  const int tid = threadIdx.x, w = tid >> 6, l = tid & 63;
  const int lr = l & 15, lg = l >> 4;
  const int id = blockIdx.y * gridDim.x + blockIdx.x;   // grid (16,64)
  const int xcd = id & 7, slot = id >> 3;
  const int bh = xcd * 8 + (slot >> 4);
  const int qx = slot & 15;
  const int b = bh >> 4, h = bh & 15;
  const size_t base = (size_t)b * SEQ * DM + (size_t)h * 64;
  const u32 vs0 = (u32)(size_t)&Vs[0][0];

#define ATT_STAGE(d, kv0)                                                       \
  {                                                                             \
    int u = tid, row = u >> 3, sl = u & 7;                                      \
    gload16((char*)Ks + (d) * 8192 + (size_t)w * 1024,                          \
            Kb + base + (size_t)((kv0) + row) * DM + ((sl * 8) ^ ((row & 7) << 3))); \
    u = tid + 256; row = u >> 3; sl = u & 7;                                    \
    gload16((char*)Ks + (d) * 8192 + 4096 + (size_t)w * 1024,                   \
            Kb + base + (size_t)((kv0) + row) * DM + ((sl * 8) ^ ((row & 7) << 3))); \
    u = tid;                                                                    \
    { int kv = ((u >> 5) << 2) + ((u >> 1) & 3);                                \
      int dd = (((u >> 3) & 3) << 4) + ((u & 1) << 3);                          \
      gload16((char*)Vs + (d) * 8192 + (size_t)w * 1024,                        \
              V + base + (size_t)((kv0) + kv) * DM + dd); }                     \
    u = tid + 256;                                                              \
    { int kv = ((u >> 5) << 2) + ((u >> 1) & 3);                                \
      int dd = (((u >> 3) & 3) << 4) + ((u & 1) << 3);                          \
      gload16((char*)Vs + (d) * 8192 + 4096 + (size_t)w * 1024,                 \
              V + base + (size_t)((kv0) + kv) * DM + dd); }                     \
  }

  #pragma unroll 1
  for (int pass = 0; pass < 2; ++pass) {
    const int qt = pass ? (31 - qx) : qx;
    const int q0 = qt * 64;
    const int qg = q0 + w * 16 + lr;          // this lane's softmax row
    const size_t qrow = base + (size_t)qg * DM;
    const bf16_8 qf0 = *(const bf16_8*)&Q[qrow + lg * 8];
    const bf16_8 qf1 = *(const bf16_8*)&Q[qrow + 32 + lg * 8];

    f32x4 o[4] = {};
    float mr = -3.0e38f, ls = 0.0f;
    const int nt = qt + 1;
    ATT_STAGE(0, 0)
    int cur = 0;

    for (int t = 0; t < nt; ++t) {
      const int kv0 = t * 64;
      if (t + 1 < nt) { ATT_STAGE(cur ^ 1, kv0 + 64) VMCNT4; }
      else VMCNT0;
      SBAR; SCHED0;

      // QK^T swapped: mfma(K, Q)
      f32x4 s[4];
      const u16* kbuf = &Ks[cur][0];
      #pragma unroll
      for (int h0 = 0; h0 < 4; ++h0) {
        const int row = h0 * 16 + lr;
        bf16_8 k0 = *(const bf16_8*)&kbuf[row * 64 + ((lg * 8) ^ ((lr & 7) << 3))];
        bf16_8 k1 = *(const bf16_8*)&kbuf[row * 64 + ((32 + lg * 8) ^ ((lr & 7) << 3))];
        f32x4 z = {};
        z = __builtin_amdgcn_mfma_f32_16x16x32_bf16(k0, qf0, z, 0, 0, 0);
        z = __builtin_amdgcn_mfma_f32_16x16x32_bf16(k1, qf1, z, 0, 0, 0);
        s[h0] = z;
      }

      // causal mask (wave-uniform skip for interior tiles)
      if (kv0 + 63 > q0 + w * 16) {
        #pragma unroll
        for (int h0 = 0; h0 < 4; ++h0) {
          int kb = kv0 + h0 * 16 + lg * 4;
          #pragma unroll
          for (int r = 0; r < 4; ++r)
            if (kb + r > qg) s[h0][r] = -3.0e38f;
        }
      }

      // row max (q = lr): in-lane + 2 shfl
      float pm = s[0][0];
      #pragma unroll
      for (int h0 = 0; h0 < 4; ++h0)
        #pragma unroll
        for (int r = 0; r < 4; ++r) pm = fmaxf(pm, s[h0][r]);
      pm = fmaxf(pm, __shfl_xor(pm, 16, 64));
      pm = fmaxf(pm, __shfl_xor(pm, 32, 64));

      // defer-max (T13): rescale only when max grew past threshold
      if (!__all(pm - mr <= 8.0f)) {
        float mnew = fmaxf(mr, pm);
        float alpha = __expf(mr - mnew);
        mr = mnew;
        ls *= alpha;
        #pragma unroll
        for (int r = 0; r < 4; ++r) {
          float ar = __shfl(alpha, lg * 4 + r, 64);
          o[0][r] *= ar; o[1][r] *= ar; o[2][r] *= ar; o[3][r] *= ar;
        }
      }

      // P = exp(s - mr); row-sum; packed b64 writes to Ps (swizzled)
      float rs = 0.0f;
      #pragma unroll
      for (int h0 = 0; h0 < 4; ++h0) {
        float p0 = __expf(s[h0][0] - mr);
        float p1 = __expf(s[h0][1] - mr);
        float p2 = __expf(s[h0][2] - mr);
        float p3 = __expf(s[h0][3] - mr);
        rs += (p0 + p1) + (p2 + p3);
        union { u16 hh[4]; uint2 u; } pk;
        pk.hh[0] = f2b(p0); pk.hh[1] = f2b(p1); pk.hh[2] = f2b(p2); pk.hh[3] = f2b(p3);
        int e = (h0 * 16 + lg * 4) ^ ((lr & 7) << 3);
        *(uint2*)&Ps[w][lr * 64 + e] = pk.u;
      }
      rs += __shfl_xor(rs, 16, 64);
      rs += __shfl_xor(rs, 32, 64);
      ls += rs;

      // PV: o += P(16x64) * V(64x64); V^T fragments via ds_read_b64_tr_b16
      const u32 vb = vs0 + (u32)(cur * 8192);
      #pragma unroll
      for (int kc = 0; kc < 2; ++kc) {
        bf16_8 pf = *(const bf16_8*)&Ps[w][lr * 64 + (((kc * 32 + lg * 8) ^ ((lr & 7) << 3)))];
        uint2 t0[4], t1[4];
        #pragma unroll
        for (int n = 0; n < 4; ++n) {
          u32 a0 = vb + (u32)((((kc * 8 + lg * 2 + 0) * 4 + n) * 128) + lr * 8);
          u32 a1 = vb + (u32)((((kc * 8 + lg * 2 + 1) * 4 + n) * 128) + lr * 8);
          t0[n] = tr_read(a0);
          t1[n] = tr_read(a1);
        }
        asm volatile("s_waitcnt lgkmcnt(0)" ::: "memory");
        SCHED0;
        #pragma unroll
        for (int n = 0; n < 4; ++n) {
          union { uint2 u2[2]; bf16_8 v; } vf;
          vf.u2[0] = t0[n]; vf.u2[1] = t1[n];
          o[n] = __builtin_amdgcn_mfma_f32_16x16x32_bf16(pf, vf.v, o[n], 0, 0, 0);
        }
      }
      SCHED0; SBAR;
      cur ^= 1;
    }

    #pragma unroll
    for (int r = 0; r < 4; ++r) {
      float inv = 1.0f / __shfl(ls, lg * 4 + r, 64);
      size_t row = (size_t)b * SEQ + q0 + w * 16 + lg * 4 + r;
      #pragma unroll
      for (int n = 0; n < 4; ++n)
        CTX[row * DM + h * 64 + n * 16 + lr] = f2b(o[n][r] * inv);
    }
  }
#undef ATT_STAGE
}

// ---------------- launch ----------------
// ALL inputs f32 (reference dtypes); output f32. bf16 used internally only.
// workspace layout (MB): peak 144
//   [0,32)   bf16 weights: WQ 0, WK 2, WV 4, WO 6, W1 8, W3 16, W2 24
//   [32,48)  XN  (xn, later yn)
//   [48,64)  Qb   \
//   [64,80)  Kb    |-- dead after attn/WO; FFIN [48,112) reuses them
//   [80,96)  Vb    |
//   [96,112) CTX  /
//   [112,144) Y (f32)
extern "C" void kernel_launch(void* const* d_in, const int* in_sizes, int n_in,
                              void* d_out, int out_size, void* d_ws, size_t ws_size,
                              hipStream_t stream) {
  const float* x  = (const float*)d_in[0];
  const float* wq = (const float*)d_in[1];
  const float* wk = (const float*)d_in[2];
  const float* wv = (const float*)d_in[3];
  const float* wo = (const float*)d_in[4];
  const float* g1 = (const float*)d_in[5];
  const float* g2 = (const float*)d_in[6];
  const float* w1 = (const float*)d_in[7];
  const float* w2 = (const float*)d_in[8];   // [1024][4096]
  const float* w3 = (const float*)d_in[9];   // [4096][1024]

  char* ws = (char*)d_ws;
  const size_t MB = 1024 * 1024;
  u16*  WQb  = (u16*)(ws +  0 * MB);
  u16*  WKb  = (u16*)(ws +  2 * MB);
  u16*  WVb  = (u16*)(ws +  4 * MB);
  u16*  WOb  = (u16*)(ws +  6 * MB);
  u16*  W1b  = (u16*)(ws +  8 * MB);
  u16*  W3b  = (u16*)(ws + 16 * MB);
  u16*  W2b  = (u16*)(ws + 24 * MB);
  u16*  XN   = (u16*)(ws + 32 * MB);   // xn, later yn
  u16*  Qb   = (u16*)(ws + 48 * MB);
  u16*  Kb   = (u16*)(ws + 64 * MB);
  u16*  Vb   = (u16*)(ws + 80 * MB);
  u16*  CTX  = (u16*)(ws + 96 * MB);
  float* Y   = (float*)(ws + 112 * MB);
  u16*  FFIN = (u16*)(ws + 48 * MB);   // reuses Qb..CTX (dead after WO gemm)

  // weights -> bf16
  cvt_bf16<<<1024, 256, 0, stream>>>(wq, WQb, 1048576);
  cvt_bf16<<<1024, 256, 0, stream>>>(wk, WKb, 1048576);
  cvt_bf16<<<1024, 256, 0, stream>>>(wv, WVb, 1048576);
  cvt_bf16<<<1024, 256, 0, stream>>>(wo, WOb, 1048576);
  cvt_bf16<<<4096, 256, 0, stream>>>(w1, W1b, 4194304);
  cvt_bf16<<<4096, 256, 0, stream>>>(w3, W3b, 4194304);
  cvt_bf16<<<4096, 256, 0, stream>>>(w2, W2b, 4194304);

  // xn = rmsnorm(x, g1)
  rmsnorm_k<<<T_TOK, 256, 0, stream>>>(x, g1, XN);

  // Q,K,V projections (fused)
  gemm_qkv<<<dim3(24, 64), 256, 0, stream>>>(XN, WQb, WKb, WVb, Qb, Kb, Vb);

  // RoPE (scale 1/sqrt(dk) folded into Q)
  rope_k<<<16384, 256, 0, stream>>>(Qb, 0.125f);
  rope_k<<<16384, 256, 0, stream>>>(Kb, 1.0f);

  // attention
  attn_k<<<dim3(16, 64), 256, 0, stream>>>(Qb, Kb, Vb, CTX);

  // y = x + ctx @ wo^T   (f32)
  gemm_nt<1><<<dim3(8, 64), 256, 0, stream>>>(CTX, WOb, nullptr, Y, x, nullptr, 1024, 1024);

  // yn = rmsnorm(y, g2)
  rmsnorm_k<<<T_TOK, 256, 0, stream>>>(Y, g2, XN);

  // a = yn @ w1^T ; ffin = silu(a) * (yn @ w3^T)   (in-place on FFIN)
  gemm_nt<0><<<dim3(32, 64), 256, 0, stream>>>(XN, W1b, FFIN, nullptr, nullptr, nullptr, 4096, 1024);
  gemm_nt<2><<<dim3(32, 64), 256, 0, stream>>>(XN, W3b, FFIN, nullptr, nullptr, FFIN, 4096, 1024);

  // out = y + ffin @ w2^T  (f32 output)
  gemm_nt<3><<<dim3(8, 64), 256, 0, stream>>>(FFIN, W2b, nullptr, (float*)d_out, Y, nullptr, 1024, 4096);
}